// Round 4
// baseline (479.672 us; speedup 1.0000x reference)
//
#include <hip/hip_runtime.h>
#include <hip/hip_bf16.h>

// Problem constants
#define B_    1024
#define NOBJ  128
#define RREL  32
#define DIM   512
#define MTOT  32768   // B_*RREL

typedef __bf16 bf16x8 __attribute__((ext_vector_type(8)));
typedef float  f32x4  __attribute__((ext_vector_type(4)));
typedef unsigned short us;

__device__ __forceinline__ us f2bf(float f) {
    unsigned int u = __float_as_uint(f);
    u += 0x7FFFu + ((u >> 16) & 1u);           // round-to-nearest-even
    return (us)(u >> 16);
}
__device__ __forceinline__ float bf2f(us h) {
    return __uint_as_float(((unsigned int)h) << 16);
}

__device__ __forceinline__ void load16_to_lds(const us* g, us* l) {
    // per-lane global address; LDS dest = wave-uniform base + lane*16
    __builtin_amdgcn_global_load_lds((const __attribute__((address_space(1))) void*)g,
                                     (__attribute__((address_space(3))) void*)l,
                                     16, 0, 0);
}

__device__ __forceinline__ bf16x8 cvt8(float4 a, float4 b) {
    bf16x8 v;
    v[0] = (__bf16)a.x; v[1] = (__bf16)a.y; v[2] = (__bf16)a.z; v[3] = (__bf16)a.w;
    v[4] = (__bf16)b.x; v[5] = (__bf16)b.y; v[6] = (__bf16)b.z; v[7] = (__bf16)b.w;
    return v;
}

// ---------------------------------------------------------------------------
// Merged weight prep: 4 matrices f32 (K x N) -> bf16 (N x K) in one dispatch.
// 32x32 LDS tile; block id selects the matrix.
// ---------------------------------------------------------------------------
__global__ __launch_bounds__(256) void prep_weights(
        const float* __restrict__ fw, const float* __restrict__ gw,
        const float* __restrict__ w1, const float* __restrict__ w2,
        us* __restrict__ WfT, us* __restrict__ WgT,
        us* __restrict__ W1T, us* __restrict__ W2T) {
    __shared__ float t32[32][33];
    int id = blockIdx.x;
    const float* in; us* out; int K, N, local;
    if (id < 512)      { in = fw; out = WfT; K = 1024; N = 512; local = id; }
    else if (id < 768) { in = gw; out = WgT; K = 512;  N = 512; local = id - 512; }
    else if (id < 896) { in = w1; out = W1T; K = 512;  N = 256; local = id - 768; }
    else               { in = w2; out = W2T; K = 256;  N = 128; local = id - 896; }
    int tilesN = N >> 5;
    int bk = (local / tilesN) * 32;
    int bn = (local % tilesN) * 32;
    int t  = threadIdx.x;
    int tx = t & 31, ty = t >> 5;            // 32 x 8
#pragma unroll
    for (int i = 0; i < 4; ++i)
        t32[ty + i * 8][tx] = in[(size_t)(bk + ty + i * 8) * N + bn + tx];
    __syncthreads();
#pragma unroll
    for (int i = 0; i < 4; ++i)
        out[(size_t)(bn + ty + i * 8) * K + bk + tx] = f2bf(t32[tx][ty + i * 8]);
}

// ---------------------------------------------------------------------------
// Fused gather + stages 1+2:
//   rf = relu((s + fl*o) @ gcn_w + gcn_b) + ([s;o] @ fuse_w + fuse_b)
// A-tiles staged straight from obj_feats (f32) with in-register bf16 convert
// + ds_write_b128 (dest = tid*16B, same layout as global_load_lds append).
// B-tiles keep global_load_lds. Grid: x = n (4, fastest) for L3 reuse of the
// gathered rows across the 4 n-blocks sharing one m-block.
// ---------------------------------------------------------------------------
__global__ __launch_bounds__(256, 2) void gemm_fused12(
        const float* __restrict__ obj,   // B*128 x 512 f32
        const int*   __restrict__ pairs, // M x 2
        const us* __restrict__ WfT,      // 512 x 1024 (N x K)
        const us* __restrict__ WgT,      // 512 x 512
        const float* __restrict__ fuse_b, const float* __restrict__ gcn_b,
        us* __restrict__ rf) {
    __shared__ __align__(16) us ldsA[128 * 32];
    __shared__ __align__(16) us ldsB[128 * 32];

    int tid  = threadIdx.x;
    int wid  = tid >> 6;
    int lane = tid & 63;
    int wm   = wid & 1;
    int wn   = wid >> 1;
    int n0   = blockIdx.x * 128;   // fast
    int m0   = blockIdx.y * 128;   // slow

    f32x4 accF[4][4], accG[4][4];
#pragma unroll
    for (int i = 0; i < 4; ++i)
#pragma unroll
        for (int j = 0; j < 4; ++j)
#pragma unroll
            for (int k = 0; k < 4; ++k) { accF[i][j][k] = 0.0f; accG[i][j][k] = 0.0f; }

    int r = tid >> 2, c = tid & 3;           // staging: row r (0..63), 8-elem chunk c

    // per-thread gather pointers for A-rows r and r+64
    int ma = m0 + r, mb = m0 + 64 + r;
    int2 pa = ((const int2*)pairs)[ma];
    int2 pb = ((const int2*)pairs)[mb];
    const float* sA_ = obj + ((size_t)((ma >> 5) * NOBJ) + pa.x) * DIM;
    const float* oA_ = obj + ((size_t)((ma >> 5) * NOBJ) + pa.y) * DIM;
    const float* sB_ = obj + ((size_t)((mb >> 5) * NOBJ) + pb.x) * DIM;
    const float* oB_ = obj + ((size_t)((mb >> 5) * NOBJ) + pb.y) * DIM;
    float flA = (pa.x != pa.y) ? 1.0f : 0.0f;
    float flB = (pb.x != pb.y) ? 1.0f : 0.0f;

    us* la0 = ldsA + tid * 8;                // row r, chunk c (tid*16B)
    us* la1 = ldsA + 2048 + tid * 8;         // row 64+r
    us* lb0 = ldsB + wid * 512;              // global_load_lds wave base
    us* lb1 = ldsB + 2048 + wid * 512;

    int arow = wm * 64 + (lane & 15);
    int brow = wn * 64 + (lane & 15);
    int koff = (lane >> 4) * 8;

    // ---- phase A: init_rel accumulation, K=1024, A = [s ; o] ----
    {
        const us* bg0 = WfT + (size_t)(n0 + r)      * 1024 + c * 8;
        const us* bg1 = WfT + (size_t)(n0 + 64 + r) * 1024 + c * 8;
        for (int k0 = 0; k0 < 1024; k0 += 32) {
            int kk = k0 & 511;
            const float* p0 = (k0 < 512) ? sA_ : oA_;
            const float* p1 = (k0 < 512) ? sB_ : oB_;
            float4 x0 = *(const float4*)(p0 + kk + c * 8);
            float4 x1 = *(const float4*)(p0 + kk + c * 8 + 4);
            float4 y0 = *(const float4*)(p1 + kk + c * 8);
            float4 y1 = *(const float4*)(p1 + kk + c * 8 + 4);
            __syncthreads();                 // prev iter's LDS reads done
            *(bf16x8*)la0 = cvt8(x0, x1);
            *(bf16x8*)la1 = cvt8(y0, y1);
            load16_to_lds(bg0 + k0, lb0);
            load16_to_lds(bg1 + k0, lb1);
            __syncthreads();
            bf16x8 a[4], b[4];
#pragma unroll
            for (int i = 0; i < 4; ++i)
                a[i] = *(const bf16x8*)(ldsA + (arow + i * 16) * 32 + koff);
#pragma unroll
            for (int j = 0; j < 4; ++j)
                b[j] = *(const bf16x8*)(ldsB + (brow + j * 16) * 32 + koff);
#pragma unroll
            for (int i = 0; i < 4; ++i)
#pragma unroll
                for (int j = 0; j < 4; ++j)
                    accF[i][j] = __builtin_amdgcn_mfma_f32_16x16x32_bf16(a[i], b[j], accF[i][j], 0, 0, 0);
        }
    }
    // ---- phase B: gcn accumulation, K=512, A = s + fl*o (f32 add, then bf16) ----
    {
        const us* bg0 = WgT + (size_t)(n0 + r)      * 512 + c * 8;
        const us* bg1 = WgT + (size_t)(n0 + 64 + r) * 512 + c * 8;
        for (int k0 = 0; k0 < 512; k0 += 32) {
            const float* a0 = sA_ + k0 + c * 8;
            const float* a1 = oA_ + k0 + c * 8;
            const float* b0 = sB_ + k0 + c * 8;
            const float* b1 = oB_ + k0 + c * 8;
            float4 sx = *(const float4*)(a0);
            float4 sy = *(const float4*)(a0 + 4);
            float4 ox = *(const float4*)(a1);
            float4 oy = *(const float4*)(a1 + 4);
            float4 tx = *(const float4*)(b0);
            float4 ty = *(const float4*)(b0 + 4);
            float4 ux = *(const float4*)(b1);
            float4 uy = *(const float4*)(b1 + 4);
            __syncthreads();
            float4 m0v, m1v, m2v, m3v;
            m0v.x = fmaf(flA, ox.x, sx.x); m0v.y = fmaf(flA, ox.y, sx.y);
            m0v.z = fmaf(flA, ox.z, sx.z); m0v.w = fmaf(flA, ox.w, sx.w);
            m1v.x = fmaf(flA, oy.x, sy.x); m1v.y = fmaf(flA, oy.y, sy.y);
            m1v.z = fmaf(flA, oy.z, sy.z); m1v.w = fmaf(flA, oy.w, sy.w);
            m2v.x = fmaf(flB, ux.x, tx.x); m2v.y = fmaf(flB, ux.y, tx.y);
            m2v.z = fmaf(flB, ux.z, tx.z); m2v.w = fmaf(flB, ux.w, tx.w);
            m3v.x = fmaf(flB, uy.x, ty.x); m3v.y = fmaf(flB, uy.y, ty.y);
            m3v.z = fmaf(flB, uy.z, ty.z); m3v.w = fmaf(flB, uy.w, ty.w);
            *(bf16x8*)la0 = cvt8(m0v, m1v);
            *(bf16x8*)la1 = cvt8(m2v, m3v);
            load16_to_lds(bg0 + k0, lb0);
            load16_to_lds(bg1 + k0, lb1);
            __syncthreads();
            bf16x8 a[4], b[4];
#pragma unroll
            for (int i = 0; i < 4; ++i)
                a[i] = *(const bf16x8*)(ldsA + (arow + i * 16) * 32 + koff);
#pragma unroll
            for (int j = 0; j < 4; ++j)
                b[j] = *(const bf16x8*)(ldsB + (brow + j * 16) * 32 + koff);
#pragma unroll
            for (int i = 0; i < 4; ++i)
#pragma unroll
                for (int j = 0; j < 4; ++j)
                    accG[i][j] = __builtin_amdgcn_mfma_f32_16x16x32_bf16(a[i], b[j], accG[i][j], 0, 0, 0);
        }
    }

    // epilogue: C/D layout col = lane&15, row = (lane>>4)*4 + reg
    int crow  = wm * 64 + (lane >> 4) * 4;
    int ccol0 = wn * 64 + (lane & 15);
    float bf_[4], bg_[4];
#pragma unroll
    for (int j = 0; j < 4; ++j) {
        bf_[j] = fuse_b[n0 + ccol0 + j * 16];
        bg_[j] = gcn_b [n0 + ccol0 + j * 16];
    }
#pragma unroll
    for (int i = 0; i < 4; ++i)
#pragma unroll
        for (int j = 0; j < 4; ++j) {
            int col = n0 + ccol0 + j * 16;
#pragma unroll
            for (int jj = 0; jj < 4; ++jj) {
                int row = m0 + crow + i * 16 + jj;
                float v = fmaxf(accG[i][j][jj] + bg_[j], 0.0f) + accF[i][j][jj] + bf_[j];
                rf[(size_t)row * 512 + col] = f2bf(v);
            }
        }
}

// ---------------------------------------------------------------------------
// Fused tail, 64-row blocks (512 blocks -> 2 blocks/CU):
//   h1 = relu(rf@W1+b1); h2 = relu(h1@W2+b2); out = softmax(h2@W3+b3)
// fc1: 4 waves across N=256 (64 cols each). fc2: 2x2 (N-half x K-half) with
// cross-wave f32 reduction through LDS. Head: 4 threads/row + shfl_xor.
// LDS overlay: H2 over stage region, red over dead H1. Total ~57.9 KB.
// ---------------------------------------------------------------------------
#define H1S 264   // shorts (132 floats) per row, pad 8
#define H2S 136
__global__ __launch_bounds__(256, 2) void tail_kernel(
        const us* __restrict__ rf,   // M x 512
        const us* __restrict__ W1T,  // 256 x 512 (N x K)
        const us* __restrict__ W2T,  // 128 x 256
        const float* __restrict__ b1, const float* __restrict__ b2,
        const float* __restrict__ w3, const float* __restrict__ b3,
        float* __restrict__ out) {
    __shared__ __align__(16) unsigned char pool[57888];
    us*    sA   = (us*)(pool);            //  4 KB: A stage 64x32
    us*    sB   = (us*)(pool + 4096);     // 16 KB: B stage (256x32 or 2x128x32)
    us*    sH2  = (us*)(pool);            // 17 KB overlay on stage (h2 64x136)
    us*    sH1  = (us*)(pool + 20480);    // 33.8 KB: h1 64x264
    float* sRed = (float*)(pool + 20480); // overlay: fc2 partials 64x132
    float* sW3  = (float*)(pool + 54272); // 3.5 KB
    float* sB3  = (float*)(pool + 57856);

    int tid  = threadIdx.x;
    int wid  = tid >> 6;
    int lane = tid & 63;
    int m0   = blockIdx.x * 64;

    for (int i = tid; i < 128 * 7; i += 256) sW3[i] = w3[i];
    if (tid < 7) sB3[tid] = b3[tid];

    int r = tid >> 2, c = tid & 3;        // staging role: row r (0..63), chunk c
    int koff = (lane >> 4) * 8;
    int l15  = lane & 15;

    // ================= fc1: C1[64x256] = rf[64x512] @ W1T^T =================
    f32x4 acc1[4][4];
#pragma unroll
    for (int i = 0; i < 4; ++i)
#pragma unroll
        for (int j = 0; j < 4; ++j)
#pragma unroll
            for (int k = 0; k < 4; ++k) acc1[i][j][k] = 0.0f;

    {
        const us* ag = rf + (size_t)(m0 + r) * 512 + c * 8;
        us* la = sA + wid * 512;
        for (int k0 = 0; k0 < 512; k0 += 32) {
            __syncthreads();
            load16_to_lds(ag + k0, la);
#pragma unroll
            for (int q = 0; q < 4; ++q)
                load16_to_lds(W1T + (size_t)(q * 64 + r) * 512 + k0 + c * 8,
                              sB + q * 2048 + wid * 512);
            __syncthreads();
            bf16x8 a[4], b[4];
#pragma unroll
            for (int i = 0; i < 4; ++i)
                a[i] = *(const bf16x8*)(sA + (l15 + i * 16) * 32 + koff);
#pragma unroll
            for (int j = 0; j < 4; ++j)
                b[j] = *(const bf16x8*)(sB + (wid * 64 + j * 16 + l15) * 32 + koff);
#pragma unroll
            for (int i = 0; i < 4; ++i)
#pragma unroll
                for (int j = 0; j < 4; ++j)
                    acc1[i][j] = __builtin_amdgcn_mfma_f32_16x16x32_bf16(a[i], b[j], acc1[i][j], 0, 0, 0);
        }
    }
    // epilogue fc1 -> sH1 (relu + bias); wave wid owns cols wid*64..+64
#pragma unroll
    for (int i = 0; i < 4; ++i)
#pragma unroll
        for (int j = 0; j < 4; ++j) {
            int col = wid * 64 + j * 16 + l15;
            float bb = b1[col];
#pragma unroll
            for (int jj = 0; jj < 4; ++jj) {
                int row = i * 16 + (lane >> 4) * 4 + jj;
                sH1[row * H1S + col] = f2bf(fmaxf(acc1[i][j][jj] + bb, 0.0f));
            }
        }

    // ================= fc2: C2[64x128] = H1[64x256] @ W2T^T =================
    // wave (kw = wid>>1, nw = wid&1): K-half kw, N-half nw (64 cols)
    int nw = wid & 1, kw = wid >> 1;
    f32x4 acc2[4][4];
#pragma unroll
    for (int i = 0; i < 4; ++i)
#pragma unroll
        for (int j = 0; j < 4; ++j)
#pragma unroll
            for (int k = 0; k < 4; ++k) acc2[i][j][k] = 0.0f;

    for (int t = 0; t < 4; ++t) {
        __syncthreads();     // also makes sH1 visible on t==0
#pragma unroll
        for (int s = 0; s < 2; ++s)
#pragma unroll
            for (int q = 0; q < 2; ++q)
                load16_to_lds(W2T + (size_t)(q * 64 + r) * 256 + s * 128 + t * 32 + c * 8,
                              sB + s * 4096 + q * 2048 + wid * 512);
        __syncthreads();
        bf16x8 a[4], b[4];
#pragma unroll
        for (int i = 0; i < 4; ++i)
            a[i] = *(const bf16x8*)(sH1 + (l15 + i * 16) * H1S + kw * 128 + t * 32 + koff);
#pragma unroll
        for (int j = 0; j < 4; ++j)
            b[j] = *(const bf16x8*)(sB + kw * 4096 + (nw * 64 + j * 16 + l15) * 32 + koff);
#pragma unroll
        for (int i = 0; i < 4; ++i)
#pragma unroll
            for (int j = 0; j < 4; ++j)
                acc2[i][j] = __builtin_amdgcn_mfma_f32_16x16x32_bf16(a[i], b[j], acc2[i][j], 0, 0, 0);
    }
    __syncthreads();                       // H1 reads done; red may overwrite
    if (kw == 1) {                         // write partials (overlay on H1)
#pragma unroll
        for (int i = 0; i < 4; ++i)
#pragma unroll
            for (int j = 0; j < 4; ++j) {
                int col = nw * 64 + j * 16 + l15;
#pragma unroll
                for (int jj = 0; jj < 4; ++jj) {
                    int row = i * 16 + (lane >> 4) * 4 + jj;
                    sRed[row * 132 + col] = acc2[i][j][jj];
                }
            }
    }
    __syncthreads();
    if (kw == 0) {                         // combine, relu, h2 -> sH2
#pragma unroll
        for (int i = 0; i < 4; ++i)
#pragma unroll
            for (int j = 0; j < 4; ++j) {
                int col = nw * 64 + j * 16 + l15;
                float bb = b2[col];
#pragma unroll
                for (int jj = 0; jj < 4; ++jj) {
                    int row = i * 16 + (lane >> 4) * 4 + jj;
                    float v = acc2[i][j][jj] + sRed[row * 132 + col] + bb;
                    sH2[row * H2S + col] = f2bf(fmaxf(v, 0.0f));
                }
            }
    }
    __syncthreads();

    // ================= head: 4 threads per row, shfl combine ================
    int row = tid >> 2;          // 0..63
    int p   = tid & 3;           // K quarter
    float accv[7];
#pragma unroll
    for (int cc = 0; cc < 7; ++cc) accv[cc] = 0.0f;
    const us* hrow = sH2 + row * H2S + p * 32;
    for (int kk = 0; kk < 8; ++kk) {
        ushort4 u = *(const ushort4*)(hrow + kk * 4);
        float f0 = bf2f(u.x), f1 = bf2f(u.y), f2 = bf2f(u.z), f3 = bf2f(u.w);
        int k = p * 32 + kk * 4;
#pragma unroll
        for (int cc = 0; cc < 7; ++cc) {
            accv[cc] = fmaf(f0, sW3[(k + 0) * 7 + cc], accv[cc]);
            accv[cc] = fmaf(f1, sW3[(k + 1) * 7 + cc], accv[cc]);
            accv[cc] = fmaf(f2, sW3[(k + 2) * 7 + cc], accv[cc]);
            accv[cc] = fmaf(f3, sW3[(k + 3) * 7 + cc], accv[cc]);
        }
    }
#pragma unroll
    for (int cc = 0; cc < 7; ++cc) {
        accv[cc] += __shfl_xor(accv[cc], 1);
        accv[cc] += __shfl_xor(accv[cc], 2);
    }
    if (p == 0) {
        float mx = accv[0] + sB3[0];
        float lg[7];
#pragma unroll
        for (int cc = 0; cc < 7; ++cc) { lg[cc] = accv[cc] + sB3[cc]; mx = fmaxf(mx, lg[cc]); }
        float sum = 0.f;
#pragma unroll
        for (int cc = 0; cc < 7; ++cc) { lg[cc] = __expf(lg[cc] - mx); sum += lg[cc]; }
        float inv = 1.0f / sum;
#pragma unroll
        for (int cc = 0; cc < 7; ++cc) out[(size_t)(m0 + row) * 7 + cc] = lg[cc] * inv;
    }
}

// ---------------------------------------------------------------------------
extern "C" void kernel_launch(void* const* d_in, const int* in_sizes, int n_in,
                              void* d_out, int out_size, void* d_ws, size_t ws_size,
                              hipStream_t stream) {
    (void)in_sizes; (void)n_in; (void)out_size; (void)ws_size;
    const float* obj    = (const float*)d_in[0];
    const int*   pairs  = (const int*)  d_in[1];
    const float* fuse_w = (const float*)d_in[2];
    const float* fuse_b = (const float*)d_in[3];
    const float* gcn_w  = (const float*)d_in[4];
    const float* gcn_b  = (const float*)d_in[5];
    const float* fc1_w  = (const float*)d_in[6];
    const float* fc1_b  = (const float*)d_in[7];
    const float* fc2_w  = (const float*)d_in[8];
    const float* fc2_b  = (const float*)d_in[9];
    const float* fc3_w  = (const float*)d_in[10];
    const float* fc3_b  = (const float*)d_in[11];
    float* out = (float*)d_out;

    char* ws = (char*)d_ws;
    us* rf   = (us*)(ws);                    // 32 MB
    us* WfT  = (us*)(ws + (32u << 20));      //  1 MB
    us* WgT  = (us*)(ws + (34u << 20));      // 512 KB
    us* W1T  = (us*)(ws + (35u << 20));      // 256 KB
    us* W2T  = (us*)(ws + (36u << 20));      //  64 KB

    // Stage 0: merged weight transposes (f32 KxN -> bf16 NxK)
    prep_weights<<<928, 256, 0, stream>>>(fuse_w, gcn_w, fc1_w, fc2_w,
                                          WfT, WgT, W1T, W2T);

    // Stage 1+2 fused (gather inlined):
    //   rf = relu((s+fl*o)@gcn_w+gcn_b) + [s;o]@fuse_w+fuse_b
    gemm_fused12<<<dim3(4, MTOT / 128), 256, 0, stream>>>(
        obj, pairs, WfT, WgT, fuse_b, gcn_b, rf);

    // Stage 3+4+5 fused: out = softmax(relu(relu(rf@W1+b1)@W2+b2)@W3+b3)
    tail_kernel<<<MTOT / 64, 256, 0, stream>>>(
        rf, W1T, W2T, fc1_b, fc2_b, fc3_w, fc3_b, out);
}

// Round 6
// 456.117 us; speedup vs baseline: 1.0516x; 1.0516x over previous
//
#include <hip/hip_runtime.h>
#include <hip/hip_bf16.h>

// Problem constants
#define B_    1024
#define NOBJ  128
#define RREL  32
#define DIM   512
#define MTOT  32768   // B_*RREL

typedef __bf16 bf16x8 __attribute__((ext_vector_type(8)));
typedef float  f32x4  __attribute__((ext_vector_type(4)));
typedef unsigned short us;

__device__ __forceinline__ us f2bf(float f) {
    unsigned int u = __float_as_uint(f);
    u += 0x7FFFu + ((u >> 16) & 1u);           // round-to-nearest-even
    return (us)(u >> 16);
}
__device__ __forceinline__ float bf2f(us h) {
    return __uint_as_float(((unsigned int)h) << 16);
}

__device__ __forceinline__ void load16_to_lds(const us* g, us* l) {
    // per-lane global address; LDS dest = wave-uniform base + lane*16
    __builtin_amdgcn_global_load_lds((const __attribute__((address_space(1))) void*)g,
                                     (__attribute__((address_space(3))) void*)l,
                                     16, 0, 0);
}

// ---------------------------------------------------------------------------
// Kernel 0: gather rows per relation, emit As=[s;o] bf16 (M x 1024) and
// Msum = bf16(s+o or s) (M x 512). Compact bf16 intermediates: unique A-data
// (96 MB) fits in L3, so fused12's 4x n-block re-reads hit L3 (R4 lesson).
// ---------------------------------------------------------------------------
__global__ __launch_bounds__(256) void gather_kernel(
        const float* __restrict__ obj, const int* __restrict__ pairs,
        us* __restrict__ As, us* __restrict__ Msum) {
    int t = threadIdx.x;
    int g = t >> 7;          // which relation of the pair
    int c = t & 127;         // float4 chunk within 512-elem row
    int base = blockIdx.x * 8;
#pragma unroll
    for (int rr = 0; rr < 4; ++rr) {
        int m  = base + rr * 2 + g;
        int b  = m >> 5;
        int p0 = pairs[(m << 1) + 0];
        int p1 = pairs[(m << 1) + 1];
        const float4* srow = (const float4*)(obj + (size_t)(b * NOBJ + p0) * DIM);
        const float4* orow = (const float4*)(obj + (size_t)(b * NOBJ + p1) * DIM);
        float4 s4 = srow[c];
        float4 o4 = orow[c];
        size_t arow = (size_t)m * 1024;
        ushort4 sb = make_ushort4(f2bf(s4.x), f2bf(s4.y), f2bf(s4.z), f2bf(s4.w));
        ushort4 ob = make_ushort4(f2bf(o4.x), f2bf(o4.y), f2bf(o4.z), f2bf(o4.w));
        *(ushort4*)(As + arow + c * 4)       = sb;
        *(ushort4*)(As + arow + 512 + c * 4) = ob;
        float4 mz = s4;
        if (p0 != p1) { mz.x += o4.x; mz.y += o4.y; mz.z += o4.z; mz.w += o4.w; }
        *(ushort4*)(Msum + (size_t)m * 512 + c * 4) =
            make_ushort4(f2bf(mz.x), f2bf(mz.y), f2bf(mz.z), f2bf(mz.w));
    }
}

// ---------------------------------------------------------------------------
// Merged weight prep: 4 matrices f32 (K x N) -> bf16 (N x K) in one dispatch.
// ---------------------------------------------------------------------------
__global__ __launch_bounds__(256) void prep_weights(
        const float* __restrict__ fw, const float* __restrict__ gw,
        const float* __restrict__ w1, const float* __restrict__ w2,
        us* __restrict__ WfT, us* __restrict__ WgT,
        us* __restrict__ W1T, us* __restrict__ W2T) {
    __shared__ float t32[32][33];
    int id = blockIdx.x;
    const float* in; us* out; int K, N, local;
    if (id < 512)      { in = fw; out = WfT; K = 1024; N = 512; local = id; }
    else if (id < 768) { in = gw; out = WgT; K = 512;  N = 512; local = id - 512; }
    else if (id < 896) { in = w1; out = W1T; K = 512;  N = 256; local = id - 768; }
    else               { in = w2; out = W2T; K = 256;  N = 128; local = id - 896; }
    int tilesN = N >> 5;
    int bk = (local / tilesN) * 32;
    int bn = (local % tilesN) * 32;
    int t  = threadIdx.x;
    int tx = t & 31, ty = t >> 5;            // 32 x 8
#pragma unroll
    for (int i = 0; i < 4; ++i)
        t32[ty + i * 8][tx] = in[(size_t)(bk + ty + i * 8) * N + bn + tx];
    __syncthreads();
#pragma unroll
    for (int i = 0; i < 4; ++i)
        out[(size_t)(bn + ty + i * 8) * K + bk + tx] = f2bf(t32[tx][ty + i * 8]);
}

// ---------------------------------------------------------------------------
// Fused stages 1+2, single merged K-loop (16 iters, 48 MFMA per barrier):
//   rf = relu(Msum @ gcn_w + gcn_b) + (As @ fuse_w + fuse_b)   -> bf16 Mx512
// ONE LDS array for all 6 tiles (R5 bug: B-tile staging addressed past the
// end of ldsA assuming ldsB adjacency — allocator doesn't guarantee it).
// Layout: A tiles at t*4096 (t=0..2: As-lo, As-hi, Msum), B tiles at
// 12288 + t*4096 (Wf-lo, Wf-hi, Wg). 48 KB LDS, 2 blocks/CU.
// ---------------------------------------------------------------------------
__global__ __launch_bounds__(256, 2) void gemm_fused12(
        const us* __restrict__ As,   // M x 1024
        const us* __restrict__ Msum, // M x 512
        const us* __restrict__ WfT,  // 512 x 1024 (N x K)
        const us* __restrict__ WgT,  // 512 x 512
        const float* __restrict__ fuse_b, const float* __restrict__ gcn_b,
        us* __restrict__ rf) {
    __shared__ __align__(16) us lds[6 * 4096];

    int tid  = threadIdx.x;
    int wid  = tid >> 6;
    int lane = tid & 63;
    int wm   = wid & 1;
    int wn   = wid >> 1;
    int n0   = blockIdx.x * 128;   // fast: 4 n-blocks of one m hit L3 together
    int m0   = blockIdx.y * 128;

    f32x4 accF[4][4], accG[4][4];
#pragma unroll
    for (int i = 0; i < 4; ++i)
#pragma unroll
        for (int j = 0; j < 4; ++j)
#pragma unroll
            for (int k = 0; k < 4; ++k) { accF[i][j][k] = 0.0f; accG[i][j][k] = 0.0f; }

    int r = tid >> 2, c = tid & 3;
    // global staging pointers (row r / r+64, 16B chunk c)
    const us* alo0 = As   + (size_t)(m0 + r)      * 1024 + c * 8;
    const us* alo1 = As   + (size_t)(m0 + 64 + r) * 1024 + c * 8;
    const us* ahi0 = alo0 + 512;
    const us* ahi1 = alo1 + 512;
    const us* ms0  = Msum + (size_t)(m0 + r)      * 512 + c * 8;
    const us* ms1  = Msum + (size_t)(m0 + 64 + r) * 512 + c * 8;
    const us* flo0 = WfT  + (size_t)(n0 + r)      * 1024 + c * 8;
    const us* flo1 = WfT  + (size_t)(n0 + 64 + r) * 1024 + c * 8;
    const us* fhi0 = flo0 + 512;
    const us* fhi1 = flo1 + 512;
    const us* gg0  = WgT  + (size_t)(n0 + r)      * 512 + c * 8;
    const us* gg1  = WgT  + (size_t)(n0 + 64 + r) * 512 + c * 8;

    us* wb = lds + wid * 512;   // wave staging base (same symbol as reads!)

    int arow = wm * 64 + (lane & 15);
    int brow = wn * 64 + (lane & 15);
    int koff = (lane >> 4) * 8;

    for (int k0 = 0; k0 < 512; k0 += 32) {
        __syncthreads();
        // A tiles (offsets within the single lds array)
        load16_to_lds(alo0 + k0, wb);               //     0 + half
        load16_to_lds(alo1 + k0, wb + 2048);
        load16_to_lds(ahi0 + k0, wb + 4096);        //  4096 + half
        load16_to_lds(ahi1 + k0, wb + 6144);
        load16_to_lds(ms0  + k0, wb + 8192);        //  8192 + half
        load16_to_lds(ms1  + k0, wb + 10240);
        // B tiles
        load16_to_lds(flo0 + k0, wb + 12288);       // 12288 + half
        load16_to_lds(flo1 + k0, wb + 14336);
        load16_to_lds(fhi0 + k0, wb + 16384);       // 16384 + half
        load16_to_lds(fhi1 + k0, wb + 18432);
        load16_to_lds(gg0  + k0, wb + 20480);       // 20480 + half
        load16_to_lds(gg1  + k0, wb + 22528);
        __syncthreads();

#pragma unroll
        for (int t = 0; t < 3; ++t) {            // As-lo*Wf-lo, As-hi*Wf-hi, Msum*Wg
            const us* tA = lds + t * 4096;
            const us* tB = lds + 12288 + t * 4096;
            bf16x8 a[4], b[4];
#pragma unroll
            for (int i = 0; i < 4; ++i)
                a[i] = *(const bf16x8*)(tA + (arow + i * 16) * 32 + koff);
#pragma unroll
            for (int j = 0; j < 4; ++j)
                b[j] = *(const bf16x8*)(tB + (brow + j * 16) * 32 + koff);
            if (t < 2) {
#pragma unroll
                for (int i = 0; i < 4; ++i)
#pragma unroll
                    for (int j = 0; j < 4; ++j)
                        accF[i][j] = __builtin_amdgcn_mfma_f32_16x16x32_bf16(a[i], b[j], accF[i][j], 0, 0, 0);
            } else {
#pragma unroll
                for (int i = 0; i < 4; ++i)
#pragma unroll
                    for (int j = 0; j < 4; ++j)
                        accG[i][j] = __builtin_amdgcn_mfma_f32_16x16x32_bf16(a[i], b[j], accG[i][j], 0, 0, 0);
            }
        }
    }

    // epilogue: C/D layout col = lane&15, row = (lane>>4)*4 + reg
    int crow  = wm * 64 + (lane >> 4) * 4;
    int ccol0 = wn * 64 + (lane & 15);
    float bf_[4], bg_[4];
#pragma unroll
    for (int j = 0; j < 4; ++j) {
        bf_[j] = fuse_b[n0 + ccol0 + j * 16];
        bg_[j] = gcn_b [n0 + ccol0 + j * 16];
    }
#pragma unroll
    for (int i = 0; i < 4; ++i)
#pragma unroll
        for (int j = 0; j < 4; ++j) {
            int col = n0 + ccol0 + j * 16;
#pragma unroll
            for (int jj = 0; jj < 4; ++jj) {
                int row = m0 + crow + i * 16 + jj;
                float v = fmaxf(accG[i][j][jj] + bg_[j], 0.0f) + accF[i][j][jj] + bf_[j];
                rf[(size_t)row * 512 + col] = f2bf(v);
            }
        }
}

// ---------------------------------------------------------------------------
// Fused tail, 64-row blocks (512 blocks -> 2 blocks/CU):
//   h1 = relu(rf@W1+b1); h2 = relu(h1@W2+b2); out = softmax(h2@W3+b3)
// fc1: 4 waves across N=256. fc2: 2x2 (N-half x K-half) with cross-wave f32
// reduction through LDS. Head: 4 threads/row + shfl_xor. LDS overlay ~57.9 KB.
// ---------------------------------------------------------------------------
#define H1S 264   // shorts (132 floats) per row, pad 8
#define H2S 136
__global__ __launch_bounds__(256, 2) void tail_kernel(
        const us* __restrict__ rf,   // M x 512
        const us* __restrict__ W1T,  // 256 x 512 (N x K)
        const us* __restrict__ W2T,  // 128 x 256
        const float* __restrict__ b1, const float* __restrict__ b2,
        const float* __restrict__ w3, const float* __restrict__ b3,
        float* __restrict__ out) {
    __shared__ __align__(16) unsigned char pool[57888];
    us*    sA   = (us*)(pool);            //  4 KB: A stage 64x32
    us*    sB   = (us*)(pool + 4096);     // 16 KB: B stage
    us*    sH2  = (us*)(pool);            // 17 KB overlay on stage (h2 64x136)
    us*    sH1  = (us*)(pool + 20480);    // 33.8 KB: h1 64x264
    float* sRed = (float*)(pool + 20480); // overlay: fc2 partials 64x132
    float* sW3  = (float*)(pool + 54272); // 3.5 KB
    float* sB3  = (float*)(pool + 57856);

    int tid  = threadIdx.x;
    int wid  = tid >> 6;
    int lane = tid & 63;
    int m0   = blockIdx.x * 64;

    for (int i = tid; i < 128 * 7; i += 256) sW3[i] = w3[i];
    if (tid < 7) sB3[tid] = b3[tid];

    int r = tid >> 2, c = tid & 3;
    int koff = (lane >> 4) * 8;
    int l15  = lane & 15;

    // ================= fc1: C1[64x256] = rf[64x512] @ W1T^T =================
    f32x4 acc1[4][4];
#pragma unroll
    for (int i = 0; i < 4; ++i)
#pragma unroll
        for (int j = 0; j < 4; ++j)
#pragma unroll
            for (int k = 0; k < 4; ++k) acc1[i][j][k] = 0.0f;

    {
        const us* ag = rf + (size_t)(m0 + r) * 512 + c * 8;
        us* la = sA + wid * 512;
        for (int k0 = 0; k0 < 512; k0 += 32) {
            __syncthreads();
            load16_to_lds(ag + k0, la);
#pragma unroll
            for (int q = 0; q < 4; ++q)
                load16_to_lds(W1T + (size_t)(q * 64 + r) * 512 + k0 + c * 8,
                              sB + q * 2048 + wid * 512);
            __syncthreads();
            bf16x8 a[4], b[4];
#pragma unroll
            for (int i = 0; i < 4; ++i)
                a[i] = *(const bf16x8*)(sA + (l15 + i * 16) * 32 + koff);
#pragma unroll
            for (int j = 0; j < 4; ++j)
                b[j] = *(const bf16x8*)(sB + (wid * 64 + j * 16 + l15) * 32 + koff);
#pragma unroll
            for (int i = 0; i < 4; ++i)
#pragma unroll
                for (int j = 0; j < 4; ++j)
                    acc1[i][j] = __builtin_amdgcn_mfma_f32_16x16x32_bf16(a[i], b[j], acc1[i][j], 0, 0, 0);
        }
    }
    // epilogue fc1 -> sH1 (relu + bias); wave wid owns cols wid*64..+64
#pragma unroll
    for (int i = 0; i < 4; ++i)
#pragma unroll
        for (int j = 0; j < 4; ++j) {
            int col = wid * 64 + j * 16 + l15;
            float bb = b1[col];
#pragma unroll
            for (int jj = 0; jj < 4; ++jj) {
                int row = i * 16 + (lane >> 4) * 4 + jj;
                sH1[row * H1S + col] = f2bf(fmaxf(acc1[i][j][jj] + bb, 0.0f));
            }
        }

    // ================= fc2: C2[64x128] = H1[64x256] @ W2T^T =================
    int nw = wid & 1, kw = wid >> 1;
    f32x4 acc2[4][4];
#pragma unroll
    for (int i = 0; i < 4; ++i)
#pragma unroll
        for (int j = 0; j < 4; ++j)
#pragma unroll
            for (int k = 0; k < 4; ++k) acc2[i][j][k] = 0.0f;

    for (int t = 0; t < 4; ++t) {
        __syncthreads();     // also makes sH1 visible on t==0
#pragma unroll
        for (int s = 0; s < 2; ++s)
#pragma unroll
            for (int q = 0; q < 2; ++q)
                load16_to_lds(W2T + (size_t)(q * 64 + r) * 256 + s * 128 + t * 32 + c * 8,
                              sB + s * 4096 + q * 2048 + wid * 512);
        __syncthreads();
        bf16x8 a[4], b[4];
#pragma unroll
        for (int i = 0; i < 4; ++i)
            a[i] = *(const bf16x8*)(sH1 + (l15 + i * 16) * H1S + kw * 128 + t * 32 + koff);
#pragma unroll
        for (int j = 0; j < 4; ++j)
            b[j] = *(const bf16x8*)(sB + kw * 4096 + (nw * 64 + j * 16 + l15) * 32 + koff);
#pragma unroll
        for (int i = 0; i < 4; ++i)
#pragma unroll
            for (int j = 0; j < 4; ++j)
                acc2[i][j] = __builtin_amdgcn_mfma_f32_16x16x32_bf16(a[i], b[j], acc2[i][j], 0, 0, 0);
    }
    __syncthreads();                       // H1 reads done; red may overwrite
    if (kw == 1) {
#pragma unroll
        for (int i = 0; i < 4; ++i)
#pragma unroll
            for (int j = 0; j < 4; ++j) {
                int col = nw * 64 + j * 16 + l15;
#pragma unroll
                for (int jj = 0; jj < 4; ++jj) {
                    int row = i * 16 + (lane >> 4) * 4 + jj;
                    sRed[row * 132 + col] = acc2[i][j][jj];
                }
            }
    }
    __syncthreads();
    if (kw == 0) {
#pragma unroll
        for (int i = 0; i < 4; ++i)
#pragma unroll
            for (int j = 0; j < 4; ++j) {
                int col = nw * 64 + j * 16 + l15;
                float bb = b2[col];
#pragma unroll
                for (int jj = 0; jj < 4; ++jj) {
                    int row = i * 16 + (lane >> 4) * 4 + jj;
                    float v = acc2[i][j][jj] + sRed[row * 132 + col] + bb;
                    sH2[row * H2S + col] = f2bf(fmaxf(v, 0.0f));
                }
            }
    }
    __syncthreads();

    // ================= head: 4 threads per row, shfl combine ================
    int row = tid >> 2;          // 0..63
    int p   = tid & 3;           // K quarter
    float accv[7];
#pragma unroll
    for (int cc = 0; cc < 7; ++cc) accv[cc] = 0.0f;
    const us* hrow = sH2 + row * H2S + p * 32;
    for (int kk = 0; kk < 8; ++kk) {
        ushort4 u = *(const ushort4*)(hrow + kk * 4);
        float f0 = bf2f(u.x), f1 = bf2f(u.y), f2 = bf2f(u.z), f3 = bf2f(u.w);
        int k = p * 32 + kk * 4;
#pragma unroll
        for (int cc = 0; cc < 7; ++cc) {
            accv[cc] = fmaf(f0, sW3[(k + 0) * 7 + cc], accv[cc]);
            accv[cc] = fmaf(f1, sW3[(k + 1) * 7 + cc], accv[cc]);
            accv[cc] = fmaf(f2, sW3[(k + 2) * 7 + cc], accv[cc]);
            accv[cc] = fmaf(f3, sW3[(k + 3) * 7 + cc], accv[cc]);
        }
    }
#pragma unroll
    for (int cc = 0; cc < 7; ++cc) {
        accv[cc] += __shfl_xor(accv[cc], 1);
        accv[cc] += __shfl_xor(accv[cc], 2);
    }
    if (p == 0) {
        float mx = accv[0] + sB3[0];
        float lg[7];
#pragma unroll
        for (int cc = 0; cc < 7; ++cc) { lg[cc] = accv[cc] + sB3[cc]; mx = fmaxf(mx, lg[cc]); }
        float sum = 0.f;
#pragma unroll
        for (int cc = 0; cc < 7; ++cc) { lg[cc] = __expf(lg[cc] - mx); sum += lg[cc]; }
        float inv = 1.0f / sum;
#pragma unroll
        for (int cc = 0; cc < 7; ++cc) out[(size_t)(m0 + row) * 7 + cc] = lg[cc] * inv;
    }
}

// ---------------------------------------------------------------------------
extern "C" void kernel_launch(void* const* d_in, const int* in_sizes, int n_in,
                              void* d_out, int out_size, void* d_ws, size_t ws_size,
                              hipStream_t stream) {
    (void)in_sizes; (void)n_in; (void)out_size; (void)ws_size;
    const float* obj    = (const float*)d_in[0];
    const int*   pairs  = (const int*)  d_in[1];
    const float* fuse_w = (const float*)d_in[2];
    const float* fuse_b = (const float*)d_in[3];
    const float* gcn_w  = (const float*)d_in[4];
    const float* gcn_b  = (const float*)d_in[5];
    const float* fc1_w  = (const float*)d_in[6];
    const float* fc1_b  = (const float*)d_in[7];
    const float* fc2_w  = (const float*)d_in[8];
    const float* fc2_b  = (const float*)d_in[9];
    const float* fc3_w  = (const float*)d_in[10];
    const float* fc3_b  = (const float*)d_in[11];
    float* out = (float*)d_out;

    char* ws = (char*)d_ws;
    us* As   = (us*)(ws);                    // 64 MB
    us* Msum = (us*)(ws + (64u  << 20));     // 32 MB
    us* rf   = (us*)(ws + (96u  << 20));     // 32 MB
    us* WfT  = (us*)(ws + (128u << 20));     //  1 MB
    us* WgT  = (us*)(ws + (129u << 20));     // 512 KB
    us* W1T  = (us*)(ws + (130u << 20));     // 256 KB
    us* W2T  = (us*)(ws + (131u << 20));     //  64 KB

    // Stage 0: gather + merged weight transposes
    gather_kernel<<<MTOT / 8, 256, 0, stream>>>(obj, pairs, As, Msum);
    prep_weights<<<928, 256, 0, stream>>>(fuse_w, gcn_w, fc1_w, fc2_w,
                                          WfT, WgT, W1T, W2T);

    // Stage 1+2 fused (merged K-loop): rf = relu(Msum@gcn_w+b) + As@fuse_w+b
    gemm_fused12<<<dim3(4, MTOT / 128), 256, 0, stream>>>(
        As, Msum, WfT, WgT, fuse_b, gcn_b, rf);

    // Stage 3+4+5 fused: out = softmax(relu(relu(rf@W1+b1)@W2+b2)@W3+b3)
    tail_kernel<<<MTOT / 64, 256, 0, stream>>>(
        rf, W1T, W2T, fc1_b, fc2_b, fc3_w, fc3_b, out);
}